// Round 5
// baseline (61.567 us; speedup 1.0000x reference)
//
#include <hip/hip_runtime.h>
#include <utility>

#define NQ 14
#define NST (1 << NQ)      // 16384
#define THREADS 1024

// ---------------- compile-time schedule ----------------
struct PassD {
    unsigned short comboS[16];  // pre-swizzled xor offsets (element units)
    unsigned short rows[4];     // R row (base-parity mask) per tile bit
    unsigned short tmask[4];    // C column (tile span mask) per tile bit
    unsigned short crx_widx[3]; // CRX gate weight indices (chain at tile bits g,g+1)
    unsigned short ry_widx[3];  // folded next-block RY weight indices
    unsigned char  ry_tb[3];    // tile bit each folded RY acts on
    unsigned char  ncrx;        // 2 or 3
    unsigned char  nry;         // 0..3
    short          rzidx;       // >=0: fold RZ layer before CRX chain
    unsigned char  measfold;    // 1: fold measurement, skip store
};
struct RZD  { unsigned short rows_ng[10]; unsigned short widx_ng[10]; unsigned short widx_g[4]; };
struct AllD { PassD pass[20]; RZD rz[4]; unsigned short meas_rows_ng[10]; int npass; };

__host__ __device__ constexpr int swz(int i) { return i ^ ((((i >> 1) ^ (i >> 3) ^ (i >> 5))) & 31); }

constexpr void fill_geom(PassD& P, const unsigned short* R, const unsigned short* C, const int* tb)
{
    for (int i = 0; i < 4; ++i) { P.tmask[i] = C[tb[i]]; P.rows[i] = R[tb[i]]; }
    for (int j = 0; j < 16; ++j) {
        unsigned short x = 0;
        for (int i = 0; i < 4; ++i) if ((j >> i) & 1) x = (unsigned short)(x ^ P.tmask[i]);
        P.comboS[j] = (unsigned short)swz(x);
    }
}

constexpr void ring(unsigned short* R, unsigned short* C) {
    for (int q = 0; q < NQ; ++q) {
        int cb = 13 - q, tb = 13 - ((q + 1) % NQ);
        R[tb] = (unsigned short)(R[tb] ^ R[cb]);
        C[cb] = (unsigned short)(C[cb] ^ C[tb]);
    }
}

constexpr AllD build_desc() {
    AllD A{};
    unsigned short R[NQ] = {}, C[NQ] = {};
    for (int k = 0; k < NQ; ++k) { R[k] = (unsigned short)(1u << k); C[k] = (unsigned short)(1u << k); }
    int np = 0;
    const int tiles[5][4] = {{13,12,11,10},{10,9,8,7},{7,6,5,4},{4,3,2,1},{1,0,13,2}};
    const int gfirst[5]   = {0, 3, 6, 9, 12};
    const int ngate[5]    = {3, 3, 3, 3, 2};
    const int rybits[5][3]= {{11,12,0},{10,9,8},{7,6,5},{4,3,2},{13,1,0}};
    const int nryp[5]     = {2, 3, 3, 3, 3};

    for (int blk = 0; blk < 4; ++blk) {
        ring(R, C);   // CNOT ring = pure relabeling
        for (int pi = 0; pi < 5; ++pi) {
            PassD& P = A.pass[np];
            fill_geom(P, R, C, tiles[pi]);
            P.ncrx = (unsigned char)ngate[pi];
            for (int g = 0; g < 3; ++g)
                P.crx_widx[g] = (unsigned short)((g < ngate[pi]) ? blk*42 + 28 + gfirst[pi] + g : 0);
            if (blk < 3) {
                P.nry = (unsigned char)nryp[pi];
                for (int g = 0; g < 3; ++g) {
                    if (g < nryp[pi]) {
                        int k = rybits[pi][g];                       // state bit
                        P.ry_widx[g] = (unsigned short)((blk + 1)*42 + (13 - k));
                        int t = 0;
                        for (int i = 0; i < 4; ++i) if (tiles[pi][i] == k) t = i;
                        P.ry_tb[g] = (unsigned char)t;
                    } else { P.ry_widx[g] = 0; P.ry_tb[g] = 0; }
                }
            } else { P.nry = 0; for (int g = 0; g < 3; ++g) { P.ry_widx[g] = 0; P.ry_tb[g] = 0; } }
            P.rzidx = (short)((pi == 0) ? blk : -1);
            P.measfold = (unsigned char)((blk == 3 && pi == 4) ? 1 : 0);
            if (pi == 0) {
                RZD& Z = A.rz[blk];
                for (int i = 0; i < 4; ++i)
                    Z.widx_g[i] = (unsigned short)(blk*42 + 14 + (13 - tiles[0][i]));
                int t = 0;
                for (int q = 4; q < NQ; ++q, ++t) {
                    Z.rows_ng[t] = R[13 - q];
                    Z.widx_ng[t] = (unsigned short)(blk*42 + 14 + q);
                }
            }
            ++np;
        }
        if (blk == 3)
            for (int t = 0; t < 10; ++t) A.meas_rows_ng[t] = R[13 - (1 + t)];
    }
    A.npass = np;
    return A;
}

constexpr AllD A = build_desc();
static_assert(A.npass == 20, "expected 20 passes");

// flat gate-weight-index table (slots 0-2 CRX, 3-5 RY)
struct GWT { unsigned short w[20][6]; };
constexpr GWT build_gwt() {
    GWT g{};
    for (int p = 0; p < 20; ++p) {
        for (int s = 0; s < 3; ++s) g.w[p][s]     = A.pass[p].crx_widx[s];
        for (int s = 0; s < 3; ++s) g.w[p][3 + s] = A.pass[p].ry_widx[s];
    }
    return g;
}
constexpr GWT GW = build_gwt();

// ---------------- GF(2) machinery for wave-closed pass pairing ----------------
constexpr int parity14(unsigned v) { v ^= v >> 8; v ^= v >> 4; v ^= v >> 2; v ^= v >> 1; return (int)(v & 1); }
constexpr int lead(unsigned short v) { int b = 13; while (b > 0 && !((v >> b) & 1)) --b; return b; }

struct Span {
    unsigned short red[14]; int n;
    constexpr unsigned short reduce(unsigned short v) const {
        for (int i = 0; i < n; ++i) { int lb = lead(red[i]); if ((v >> lb) & 1) v = (unsigned short)(v ^ red[i]); }
        return v;
    }
    constexpr bool add(unsigned short v) {
        unsigned short r = reduce(v);
        if (!r) return false;
        red[n++] = r; return true;
    }
};

// entry = (swz(vec)<<3) | (parity_bits << 18)
// parity bits: 0..3 = rows[0..3]; 4..13 = rz rows_ng OR meas_rows_ng (per pass)
constexpr unsigned pack_entry(unsigned short vec, const PassD& P) {
    unsigned par = 0;
    for (int t = 0; t < 4; ++t) par |= (unsigned)parity14(vec & P.rows[t]) << t;
    if (P.rzidx >= 0)
        for (int t = 0; t < 10; ++t) par |= (unsigned)parity14(vec & A.rz[P.rzidx].rows_ng[t]) << (4 + t);
    if (P.measfold)
        for (int t = 0; t < 10; ++t) par |= (unsigned)parity14(vec & A.meas_rows_ng[t]) << (4 + t);
    return ((unsigned)swz(vec) << 3) | (par << 18);
}

struct LutsT { unsigned v[20][2][32]; int ok; };

constexpr LutsT build_luts() {
    LutsT L{};
    L.ok = 1;
    for (int k = 0; k < 10; ++k) {
        const PassD& P0 = A.pass[2*k];
        const PassD& P1 = A.pass[2*k + 1];
        // W = span(T0 ∪ T1) extended to dim 10
        Span SW{}; unsigned short Wb[10] = {}; int nw = 0;
        for (int i = 0; i < 4; ++i) if (SW.add(P0.tmask[i])) Wb[nw++] = P0.tmask[i];
        for (int i = 0; i < 4; ++i) if (nw < 10 && SW.add(P1.tmask[i])) Wb[nw++] = P1.tmask[i];
        for (int b = 0; b < 14 && nw < 10; ++b) {
            unsigned short e = (unsigned short)(1u << b);
            if (SW.add(e)) Wb[nw++] = e;
        }
        if (nw != 10) L.ok = 0;
        // wave-bit complement g[4] (shared by both passes of the pair)
        Span SG = SW; unsigned short g[4] = {}; int ngv = 0;
        for (int b = 0; b < 14 && ngv < 4; ++b) {
            unsigned short e = (unsigned short)(1u << b);
            if (SG.add(e)) g[ngv++] = e;
        }
        if (ngv != 4) L.ok = 0;
        for (int pp = 0; pp < 2; ++pp) {
            const PassD& P = (pp == 0) ? P0 : P1;
            int pidx = 2*k + pp;
            Span ST{};
            for (int i = 0; i < 4; ++i) ST.add(P.tmask[i]);
            // lane vectors: completion of T inside W
            unsigned short lane[6] = {}; int nl = 0;
            {
                Span STl = ST;
                for (int i = 0; i < 10 && nl < 6; ++i)
                    if (STl.add(Wb[i])) lane[nl++] = Wb[i];
            }
            if (nl != 6) L.ok = 0;
            // bank greedy: adjust lane[i] by tile-span elements so swz(lane)&15 reaches rank 4
            {
                Span low4{};
                for (int i = 0; i < 6; ++i) {
                    int done = 0;
                    for (int c = 0; c < 16 && !done; ++c) {
                        unsigned short cand = lane[i];
                        for (int b2 = 0; b2 < 4; ++b2) if ((c >> b2) & 1) cand = (unsigned short)(cand ^ P.tmask[b2]);
                        unsigned short l4 = (unsigned short)(swz(cand) & 15);
                        if (l4) {
                            Span tmp = low4;
                            if (tmp.add(l4)) { lane[i] = cand; low4 = tmp; done = 1; }
                        }
                    }
                }
            }
            // bijectivity check: T ∪ lane ∪ g spans F_2^14
            {
                Span SF{};
                for (int i = 0; i < 4; ++i) SF.add(P.tmask[i]);
                for (int i = 0; i < 6; ++i) if (!SF.add(lane[i])) L.ok = 0;
                for (int i = 0; i < 4; ++i) if (!SF.add(g[i])) L.ok = 0;
                if (SF.n != 14) L.ok = 0;
            }
            // emit LUTs: tid bits 0..4 -> lane[0..4]; bit5 -> lane[5]; bits6..9 -> g[0..3]
            for (int t = 0; t < 32; ++t) {
                unsigned short x = 0;
                for (int i = 0; i < 5; ++i) if ((t >> i) & 1) x = (unsigned short)(x ^ lane[i]);
                L.v[pidx][0][t] = pack_entry(x, P);
                unsigned short y = 0;
                if (t & 1) y = (unsigned short)(y ^ lane[5]);
                for (int i = 0; i < 4; ++i) if ((t >> (i + 1)) & 1) y = (unsigned short)(y ^ g[i]);
                L.v[pidx][1][t] = pack_entry(y, P);
            }
        }
    }
    return L;
}

constexpr LutsT LUTS = build_luts();
static_assert(LUTS.ok == 1, "LUT construction failed (rank check)");

__device__ __constant__ LutsT cLUTS = LUTS;

// ---------------- per-pass device code (fully constant-folded) ----------------
template<int Pi>
__device__ __forceinline__ void run_pass(float2* st, const float (*tabG)[6][2], const float (*tabRZ)[14],
                                         unsigned comb, float* acc)
{
    constexpr PassD Pd = A.pass[Pi];
    char* stb = (char*)st;
    const int base = (int)(comb & 0x1FFF8u);   // pre-swizzled byte offset
    const unsigned par = comb >> 18;           // parity bits

    float2 v[16];
#pragma unroll
    for (int j = 0; j < 16; ++j)
        v[j] = *(const float2*)(stb + (base ^ (Pd.comboS[j] << 3)));

    // ---- fused RZ layer (first pass of each block; before the CRX chain) ----
    if constexpr (Pd.rzidx >= 0) {
        float phi0 = 0.f;
#pragma unroll
        for (int t = 0; t < 10; ++t) {
            float h = tabRZ[Pd.rzidx][t];
            phi0 += ((par >> (4 + t)) & 1) ? h : -h;
        }
        float e0 = (par & 1) ? tabRZ[Pd.rzidx][10] : -tabRZ[Pd.rzidx][10];
        float e1 = ((par >> 1) & 1) ? tabRZ[Pd.rzidx][11] : -tabRZ[Pd.rzidx][11];
        float e2 = ((par >> 2) & 1) ? tabRZ[Pd.rzidx][12] : -tabRZ[Pd.rzidx][12];
        float e3 = ((par >> 3) & 1) ? tabRZ[Pd.rzidx][13] : -tabRZ[Pd.rzidx][13];
#pragma unroll
        for (int j = 0; j < 16; ++j) {
            float phi = phi0 + ((j & 1) ? -e0 : e0) + ((j & 2) ? -e1 : e1)
                             + ((j & 4) ? -e2 : e2) + ((j & 8) ? -e3 : e3);
            float s, c; __sincosf(phi, &s, &c);
            float2 a = v[j];
            v[j] = make_float2(a.x * c - a.y * s, a.y * c + a.x * s);
        }
    }

    // ---- CRX chain: gate g: control = tile bit g, target = tile bit g+1 ----
#pragma unroll
    for (int g = 0; g < Pd.ncrx; ++g) {
        float c = tabG[Pi][g][0], s = tabG[Pi][g][1];
        int bc = (int)((par >> g) & 1);
        float c0 = bc ? c : 1.f, s0 = bc ? s : 0.f;   // logical ctrl for jg==0
        float c1 = bc ? 1.f : c, s1 = bc ? 0.f : s;   // logical ctrl for jg==1
#pragma unroll
        for (int j = 0; j < 16; ++j) if (!((j >> (g + 1)) & 1)) {
            int j1 = j | (1 << (g + 1));
            float ce = ((j >> g) & 1) ? c1 : c0;
            float se = ((j >> g) & 1) ? s1 : s0;
            float2 a0 = v[j], a1 = v[j1];
            v[j]  = make_float2(ce * a0.x + se * a1.y, ce * a0.y - se * a1.x);
            v[j1] = make_float2(ce * a1.x + se * a0.y, ce * a1.y - se * a0.x);
        }
    }

    // ---- folded next-block RY gates ----
#pragma unroll
    for (int g = 0; g < Pd.nry; ++g) {
        int t = Pd.ry_tb[g];   // compile-time after unroll
        float c = tabG[Pi][3 + g][0], s0 = tabG[Pi][3 + g][1];
        float s = ((par >> t) & 1) ? -s0 : s0;
#pragma unroll
        for (int j = 0; j < 16; ++j) if (!((j >> t) & 1)) {
            int j1 = j | (1 << t);
            float2 a0 = v[j], a1 = v[j1];
            v[j]  = make_float2(c * a0.x - s * a1.x, c * a0.y - s * a1.y);
            v[j1] = make_float2(s * a0.x + c * a1.x, s * a0.y + c * a1.y);
        }
    }

    if constexpr (Pd.measfold != 0) {
        float psum = 0.f, pg0 = 0.f, pg1 = 0.f, pg2 = 0.f, pg3 = 0.f;
#pragma unroll
        for (int j = 0; j < 16; ++j) {
            float pj = v[j].x * v[j].x + v[j].y * v[j].y;
            psum += pj;
            if (j & 1) pg0 += pj;
            if (j & 2) pg1 += pj;
            if (j & 4) pg2 += pj;
            if (j & 8) pg3 += pj;
        }
        float s0 = (par & 1) ? -1.f : 1.f;
        float s1 = ((par >> 1) & 1) ? -1.f : 1.f;
        float s2 = ((par >> 2) & 1) ? -1.f : 1.f;
        float s3 = ((par >> 3) & 1) ? -1.f : 1.f;
        // tile state bits {1,0,13,2} = JAX qubits {12,13,0,11}
        acc[12] += s0 * (psum - 2.f * pg0);
        acc[13] += s1 * (psum - 2.f * pg1);
        acc[0]  += s2 * (psum - 2.f * pg2);
        acc[11] += s3 * (psum - 2.f * pg3);
#pragma unroll
        for (int t = 0; t < 10; ++t) {
            float sg = ((par >> (4 + t)) & 1) ? -1.f : 1.f;
            acc[1 + t] += sg * psum;
        }
    } else {
#pragma unroll
        for (int j = 0; j < 16; ++j)
            *(float2*)(stb + (base ^ (Pd.comboS[j] << 3))) = v[j];
        // wave-closed pairing: barrier only at end of each (even,odd) pair.
        // Within a pair the odd pass reads ONLY data written by the same wave
        // (same W-coset); per-wave DS ops execute in order -> no barrier needed.
        if constexpr ((Pi & 1) != 0) __syncthreads();
    }
}

template<int... I>
__device__ __forceinline__ void run_all(std::integer_sequence<int, I...>,
                                        float2* st, const float (*tabG)[6][2], const float (*tabRZ)[14],
                                        const unsigned* comb, float* acc)
{
    (run_pass<I>(st, tabG, tabRZ, comb[I], acc), ...);
}

// ---------------- main kernel ----------------
__global__ __launch_bounds__(THREADS)
void qsim_kernel(const float* __restrict__ inputs,
                 const float* __restrict__ weights,
                 float* __restrict__ out)
{
    __shared__ float2 st[NST];           // 128 KiB state
    __shared__ float  tab[256];          // product-state init tables
    __shared__ float  tabG[20][6][2];    // uniform gate (c,s) per pass/slot
    __shared__ float  tabRZ[4][14];      // RZ half-angles per block
    __shared__ float  red[THREADS / 64][NQ];

    const int b = blockIdx.x;
    const int tid = threadIdx.x;

    // ---- per-pass combined (base ^ parity) words, from compile-time LUTs ----
    unsigned comb[20];
#pragma unroll
    for (int p = 0; p < 20; ++p)
        comb[p] = cLUTS.v[p][0][tid & 31] ^ cLUTS.v[p][1][tid >> 5];

    // ---- build trig + product tables (disjoint thread ranges) ----
    if (tid < 120) {
        int p = tid / 6, sl = tid - p * 6;
        float w = weights[GW.w[p][sl]];
        float s, c; __sincosf(0.5f * w, &s, &c);
        tabG[p][sl][0] = c; tabG[p][sl][1] = s;
    } else if (tid >= 128 && tid < 128 + 56) {
        int idx = tid - 128;
        int blk = idx / 14, k = idx - blk * 14;
        unsigned wi = (k < 10) ? A.rz[blk].widx_ng[k] : A.rz[blk].widx_g[k - 10];
        tabRZ[blk][k] = 0.5f * weights[wi];
    } else if (tid >= 256 && tid < 512) {
        int t = tid - 256;
        int half = t >> 7, tt = t & 127;
        float prod = 1.f;
#pragma unroll
        for (int j = 0; j < 7; ++j) {
            int xb = j + 7 * half;
            int q  = 13 - xb;
            float a = 0.5f * (inputs[b * NQ + q] + weights[q]);   // init RY ∘ blk0 RY fold
            float s, c; __sincosf(a, &s, &c);
            prod *= ((tt >> j) & 1) ? s : c;
        }
        tab[t] = prod;
    }
    __syncthreads();

    // ---- write product state ----
#pragma unroll
    for (int j = 0; j < 16; ++j) {
        int x = tid + j * THREADS;
        st[swz(x)] = make_float2(tab[x & 127] * tab[128 + (x >> 7)], 0.f);
    }
    __syncthreads();

    float acc[NQ];
#pragma unroll
    for (int q = 0; q < NQ; ++q) acc[q] = 0.f;

    run_all(std::make_integer_sequence<int, 20>{}, st, tabG, tabRZ, comb, acc);

    // ---- block-wide reduction ----
#pragma unroll
    for (int q = 0; q < NQ; ++q) {
        float v2 = acc[q];
        v2 += __shfl_down(v2, 32);
        v2 += __shfl_down(v2, 16);
        v2 += __shfl_down(v2, 8);
        v2 += __shfl_down(v2, 4);
        v2 += __shfl_down(v2, 2);
        v2 += __shfl_down(v2, 1);
        acc[q] = v2;
    }
    const int wave = tid >> 6, lane = tid & 63;
    if (lane == 0) {
#pragma unroll
        for (int q = 0; q < NQ; ++q) red[wave][q] = acc[q];
    }
    __syncthreads();
    if (tid < NQ) {
        float v2 = 0.f;
#pragma unroll
        for (int w = 0; w < THREADS / 64; ++w) v2 += red[w][tid];
        out[b * NQ + tid] = v2;
    }
}

extern "C" void kernel_launch(void* const* d_in, const int* in_sizes, int n_in,
                              void* d_out, int out_size, void* d_ws, size_t ws_size,
                              hipStream_t stream) {
    const float* inputs  = (const float*)d_in[0];
    const float* weights = (const float*)d_in[1];
    float* out = (float*)d_out;
    const int B = in_sizes[0] / NQ;   // 256
    qsim_kernel<<<dim3(B), dim3(THREADS), 0, stream>>>(inputs, weights, out);
}